// Round 10
// baseline (30.791 us; speedup 1.0000x reference)
//
#include <hip/hip_runtime.h>
#include <hip/hip_bf16.h>

#define NB 2
#define NQS 1024
#define NKS 1024
#define DD 512
#define HH 32
#define W1S 34   // bf16 LDS stride: conflict-free B-frag reads
#define EKS 36   // f32 LDS stride for Ek: keeps b128 reads 16B-aligned

typedef __attribute__((ext_vector_type(8))) short bf16x8;
typedef __attribute__((ext_vector_type(4))) float f32x4;

static __device__ __forceinline__ float fexp2(float x) {
#if __has_builtin(__builtin_amdgcn_exp2f)
  return __builtin_amdgcn_exp2f(x);
#else
  float r; asm("v_exp_f32 %0, %1" : "=v"(r) : "v"(x)); return r;
#endif
}
static __device__ __forceinline__ float frcp(float x) {
#if __has_builtin(__builtin_amdgcn_rcpf)
  return __builtin_amdgcn_rcpf(x);
#else
  float r; asm("v_rcp_f32 %0, %1" : "=v"(r) : "v"(x)); return r;
#endif
}
// readfirstlane preserving float bits (builtin is int-typed)
static __device__ __forceinline__ float rfl_f32(float x) {
  return __int_as_float(__builtin_amdgcn_readfirstlane(__float_as_int(x)));
}

// One block = one 64k x 64q output tile. Block projects its own 128 rows
// (redundant across tiles but trivial FLOPs) -> no inter-block dependency,
// ONE kernel, no grid sync. 512 blocks x 256 thr = 2 blocks/CU resident.
__global__ __launch_bounds__(256) void fused_all(
    const float* __restrict__ keys, const float* __restrict__ queries,
    const float* __restrict__ W1, const float* __restrict__ b1,
    const float* __restrict__ W2, const float* __restrict__ b2,
    float* __restrict__ out) {
  __shared__ __hip_bfloat16 W1L[DD * W1S];  // 34.8 KB, restaged per phase
  __shared__ float EkL[64 * EKS];           // 9.2 KB
  __shared__ float EqL[64 * HH];            // 8.2 KB
  const float S = 2.8853900817779268f;      // 2*log2(e)
  const int tid = threadIdx.x;
  // XCD-bijective swizzle (512 % 8 == 0): XCD x gets kt in {2x, 2x+1}
  const int bid = blockIdx.x;
  const int swz = (bid & 7) * 64 + (bid >> 3);
  const int kt = swz >> 5, rem = swz & 31;
  const int qt = rem >> 1, b = rem & 1;
  const int l = tid & 63, w = tid >> 6;
  const int m = l & 15, kq = l >> 4;
  union Frag { bf16x8 v; __hip_bfloat16 e[8]; };

#pragma unroll
  for (int phase = 0; phase < 2; ++phase) {
    // ---- stage W1 half (512x32 f32 -> bf16 LDS stride-34) ----
    const float* w1 = W1 + (size_t)phase * DD * HH;
#pragma unroll
    for (int s = 0; s < 16; ++s) {
      const int f = tid + s * 256;
      float4 v = *(const float4*)(w1 + (size_t)f * 4);
      const int k = f >> 3, h0 = (f & 7) * 4;
      __hip_bfloat16* p = &W1L[k * W1S + h0];
      p[0] = __float2bfloat16(v.x); p[1] = __float2bfloat16(v.y);
      p[2] = __float2bfloat16(v.z); p[3] = __float2bfloat16(v.w);
    }
    __syncthreads();
    // ---- MFMA-project this block's 64 rows (16 per wave, full K) ----
    const float* src = phase ? queries + (size_t)(b * NQS + qt * 64 + w * 16 + m) * DD
                             : keys + (size_t)(b * NKS + kt * 64 + w * 16 + m) * DD;
    const float* arow = src + kq * 8;
    f32x4 acc0 = {0.f, 0.f, 0.f, 0.f}, acc1 = {0.f, 0.f, 0.f, 0.f};
#pragma unroll
    for (int s = 0; s < 16; ++s) {
      float4 a0 = *(const float4*)(arow + s * 32);
      float4 a1 = *(const float4*)(arow + s * 32 + 4);
      Frag af, bf0, bf1;
      af.e[0] = __float2bfloat16(a0.x); af.e[1] = __float2bfloat16(a0.y);
      af.e[2] = __float2bfloat16(a0.z); af.e[3] = __float2bfloat16(a0.w);
      af.e[4] = __float2bfloat16(a1.x); af.e[5] = __float2bfloat16(a1.y);
      af.e[6] = __float2bfloat16(a1.z); af.e[7] = __float2bfloat16(a1.w);
      const __hip_bfloat16* bp = &W1L[(s * 32 + kq * 8) * W1S + m];
#pragma unroll
      for (int j = 0; j < 8; ++j) {
        bf0.e[j] = bp[j * W1S];
        bf1.e[j] = bp[j * W1S + 16];
      }
      acc0 = __builtin_amdgcn_mfma_f32_16x16x32_bf16(af.v, bf0.v, acc0, 0, 0, 0);
      acc1 = __builtin_amdgcn_mfma_f32_16x16x32_bf16(af.v, bf1.v, acc1, 0, 0, 0);
    }
    // ---- exp2 epilogue into LDS (C/D: col=lane&15, row=(lane>>4)*4+reg) ----
    if (phase == 0) {
#pragma unroll
      for (int r = 0; r < 4; ++r) {
        const int rr = w * 16 + kq * 4 + r;
        EkL[rr * EKS + m] = fexp2(S * acc0[r]);
        EkL[rr * EKS + 16 + m] = fexp2(S * acc1[r]);
      }
    } else {
      const float bias0 = b1[m], bias1 = b1[16 + m];
#pragma unroll
      for (int r = 0; r < 4; ++r) {
        const int rr = w * 16 + kq * 4 + r;
        EqL[rr * HH + m] = fexp2(S * (acc0[r] + bias0));
        EqL[rr * HH + 16 + m] = fexp2(S * (acc1[r] + bias1));
      }
    }
    __syncthreads();  // phase 0: epilogue done before W1L restage; phase 1: before scoring
  }
  // ---- scoring: lane kl owns k-column, wave w owns q-rows w*16..+15 ----
  float w2v[HH];  // SGPR-resident raw weights (zero VALU arithmetic on them)
  float c0 = rfl_f32(b2[0]);
#pragma unroll
  for (int h = 0; h < HH; ++h) {
    w2v[h] = rfl_f32(W2[h]);
    c0 += w2v[h];
  }
  const int kl = l;
  float ek[HH];
#pragma unroll
  for (int i = 0; i < 8; ++i) {
    float4 v = *(const float4*)(&EkL[kl * EKS + i * 4]);  // 16B-aligned (144*kl)
    ek[i * 4 + 0] = v.x; ek[i * 4 + 1] = v.y;
    ek[i * 4 + 2] = v.z; ek[i * 4 + 3] = v.w;
  }
  float* outp = out + ((size_t)b * NQS + qt * 64 + w * 16) * NKS + kt * 64 + kl;
#pragma unroll 4
  for (int j = 0; j < 16; ++j) {
    const float* ej = &EqL[(w * 16 + j) * HH];  // wave-uniform -> LDS broadcast
    float a0 = 0.f, a1 = 0.f;
#pragma unroll
    for (int i2 = 0; i2 < 8; ++i2) {
      float4 ev = *(const float4*)(ej + i2 * 4);
      {
        const int hb = i2 * 4;  // pair (hb, hb+1)
        float da = fmaf(ek[hb + 0], ev.x, 1.f);
        float db = fmaf(ek[hb + 1], ev.y, 1.f);
        float num = fmaf(w2v[hb + 0], db, w2v[hb + 1] * da);
        a0 = fmaf(num, frcp(da * db), a0);
      }
      {
        const int hb = i2 * 4 + 2;  // pair (hb, hb+1)
        float da = fmaf(ek[hb + 0], ev.z, 1.f);
        float db = fmaf(ek[hb + 1], ev.w, 1.f);
        float num = fmaf(w2v[hb + 0], db, w2v[hb + 1] * da);
        a1 = fmaf(num, frcp(da * db), a1);
      }
    }
    outp[(size_t)j * NKS] = fmaf(-2.f, a0 + a1, c0);
  }
}

extern "C" void kernel_launch(void* const* d_in, const int* in_sizes, int n_in,
                              void* d_out, int out_size, void* d_ws, size_t ws_size,
                              hipStream_t stream) {
  const float* keys = (const float*)d_in[0];
  const float* queries = (const float*)d_in[1];
  const float* W1 = (const float*)d_in[2];
  const float* b1 = (const float*)d_in[3];
  const float* W2 = (const float*)d_in[4];
  const float* b2 = (const float*)d_in[5];
  float* out = (float*)d_out;

  hipLaunchKernelGGL(fused_all, dim3(512), dim3(256), 0, stream,
                     keys, queries, W1, b1, W2, b2, out);
}